// Round 3
// baseline (261.927 us; speedup 1.0000x reference)
//
#include <hip/hip_runtime.h>
#include <hip/hip_bf16.h>

typedef __attribute__((ext_vector_type(8))) short short8;
typedef __attribute__((ext_vector_type(4))) float floatx4;

using bf16 = __hip_bfloat16;

#define S_LEN 2048
#define DM 1024
#define NH 16
#define DH 64
#define WIN 256

// ---------- helpers ----------
__device__ __forceinline__ unsigned short f2b(float f) {
  __hip_bfloat16 h = __float2bfloat16(f);
  return *reinterpret_cast<unsigned short*>(&h);
}
__device__ __forceinline__ void lds_load16(void* lds, const void* gptr) {
  __builtin_amdgcn_global_load_lds(
      (const __attribute__((address_space(1))) unsigned int*)gptr,
      (__attribute__((address_space(3))) unsigned int*)lds, 16, 0, 0);
}

// ---------- K1: x fp32 -> bf16 ----------
__global__ __launch_bounds__(256) void k_convert_x(const float4* __restrict__ in,
                                                   ushort4* __restrict__ out) {
  int i = blockIdx.x * 256 + threadIdx.x;
  float4 v = in[i];
  ushort4 r;
  r.x = f2b(v.x); r.y = f2b(v.y); r.z = f2b(v.z); r.w = f2b(v.w);
  out[i] = r;
}

// ---------- K2: W[k][n] fp32 -> Wt[n][k] bf16 (4 matrices) ----------
__global__ __launch_bounds__(256) void k_transpose_cvt(const float* __restrict__ W0,
                                                       const float* __restrict__ W1,
                                                       const float* __restrict__ W2,
                                                       const float* __restrict__ W3,
                                                       bf16* __restrict__ out) {
  __shared__ float t[32][33];
  const float* W = (blockIdx.z == 0) ? W0 : (blockIdx.z == 1) ? W1 : (blockIdx.z == 2) ? W2 : W3;
  bf16* O = out + (size_t)blockIdx.z * 1024 * 1024;
  int x0 = blockIdx.x * 32, y0 = blockIdx.y * 32;
  int tx = threadIdx.x, ty = threadIdx.y;  // block (32,8)
  #pragma unroll
  for (int i = 0; i < 32; i += 8) t[ty + i][tx] = W[(size_t)(y0 + ty + i) * 1024 + x0 + tx];
  __syncthreads();
  #pragma unroll
  for (int i = 0; i < 32; i += 8)
    O[(size_t)(x0 + ty + i) * 1024 + y0 + tx] = __float2bfloat16(t[tx][ty + i]);
}

// ---------- K3/K5: bf16 MFMA GEMM, C = A[M][1024] * Bt[N][1024]^T ----------
// MODE 0: N=3072 (Wq|Wk|Wv) -> Qh/Kh [bh][s][64] bf16; V transposed: Vt [bh][d][s]
// MODE 1: N=1024 (Wo) -> fp32 [m][1024]
template <int MODE>
__global__ __launch_bounds__(256) void k_gemm(const bf16* __restrict__ A,
                                              const bf16* __restrict__ Bt,
                                              const float* __restrict__ bias_q,
                                              const float* __restrict__ bias_k,
                                              const float* __restrict__ bias_v,
                                              bf16* __restrict__ Qh, bf16* __restrict__ Kh,
                                              bf16* __restrict__ Vt, float* __restrict__ outF) {
  __shared__ __align__(16) bf16 As[128 * 32];
  __shared__ __align__(16) bf16 Bs[128 * 32];
  const int tid = threadIdx.x;
  const int wave = tid >> 6, lane = tid & 63;
  const int m0 = blockIdx.y * 128, n0 = blockIdx.x * 128;
  const int r0 = tid >> 2;
  const int cb = (tid & 3) * 16;
  const char* Ag = (const char*)A + (size_t)(m0 + r0) * 2048 + cb;
  const char* Bg = (const char*)Bt + (size_t)(n0 + r0) * 2048 + cb;
  char* AsW0 = (char*)As + wave * 1024;
  char* AsW1 = (char*)As + 4096 + wave * 1024;
  char* BsW0 = (char*)Bs + wave * 1024;
  char* BsW1 = (char*)Bs + 4096 + wave * 1024;
  const int wm = (wave & 1) * 64, wn = (wave >> 1) * 64;
  const int ln = lane & 15, quad = lane >> 4;

  floatx4 acc[4][4];
  #pragma unroll
  for (int i = 0; i < 4; i++)
    #pragma unroll
    for (int j = 0; j < 4; j++) acc[i][j] = (floatx4){0.f, 0.f, 0.f, 0.f};

  for (int k0 = 0; k0 < 1024; k0 += 32) {
    __syncthreads();
    lds_load16(AsW0, Ag + k0 * 2);
    lds_load16(AsW1, Ag + 64 * 2048 + k0 * 2);
    lds_load16(BsW0, Bg + k0 * 2);
    lds_load16(BsW1, Bg + 64 * 2048 + k0 * 2);
    __syncthreads();
    short8 af[4], bfr[4];
    #pragma unroll
    for (int mi = 0; mi < 4; mi++)
      af[mi] = *(const short8*)&As[(wm + mi * 16 + ln) * 32 + quad * 8];
    #pragma unroll
    for (int ni = 0; ni < 4; ni++)
      bfr[ni] = *(const short8*)&Bs[(wn + ni * 16 + ln) * 32 + quad * 8];
    #pragma unroll
    for (int mi = 0; mi < 4; mi++)
      #pragma unroll
      for (int ni = 0; ni < 4; ni++)
        acc[mi][ni] = __builtin_amdgcn_mfma_f32_16x16x32_bf16(af[mi], bfr[ni], acc[mi][ni], 0, 0, 0);
  }

  if constexpr (MODE == 0) {
    #pragma unroll
    for (int ni = 0; ni < 4; ni++) {
      int n = n0 + wn + ni * 16 + ln;  // 0..3071; g uniform across the wave's 16 ln
      int g = n >> 10, nn = n & 1023;
      int h = nn >> 6, dd = nn & 63;
      if (g == 2) {  // V: transposed layout Vt[bh][d][s], 4 consecutive s -> 8B store
        float bias = bias_v[nn];
        #pragma unroll
        for (int mi = 0; mi < 4; mi++) {
          int m = m0 + wm + mi * 16 + quad * 4;
          int b = m >> 11, s = m & 2047;
          ushort4 pk;
          pk.x = f2b(acc[mi][ni][0] + bias);
          pk.y = f2b(acc[mi][ni][1] + bias);
          pk.z = f2b(acc[mi][ni][2] + bias);
          pk.w = f2b(acc[mi][ni][3] + bias);
          *(ushort4*)&Vt[((size_t)(b * NH + h) * DH + dd) * S_LEN + s] = pk;
        }
      } else {
        const float* bp = (g == 0) ? bias_q : bias_k;
        bf16* og = (g == 0) ? Qh : Kh;
        float bias = bp[nn];
        #pragma unroll
        for (int mi = 0; mi < 4; mi++) {
          #pragma unroll
          for (int r = 0; r < 4; r++) {
            int m = m0 + wm + mi * 16 + quad * 4 + r;
            int b = m >> 11, s = m & 2047;
            og[(size_t)((b * NH + h) * S_LEN + s) * DH + dd] =
                __float2bfloat16(acc[mi][ni][r] + bias);
          }
        }
      }
    }
  } else {
    #pragma unroll
    for (int ni = 0; ni < 4; ni++) {
      int n = n0 + wn + ni * 16 + ln;
      float bias = bias_q[n];
      #pragma unroll
      for (int mi = 0; mi < 4; mi++)
        #pragma unroll
        for (int r = 0; r < 4; r++) {
          int m = m0 + wm + mi * 16 + quad * 4 + r;
          outF[(size_t)m * 1024 + n] = acc[mi][ni][r] + bias;
        }
    }
  }
}

// ---------- K4: barrier-free MFMA flash attention ----------
// grid (S/64, B*H), block 256 = 4 independent waves; each wave owns 16 queries.
// K frags and V^T frags are loaded straight from global (L1/L2-resident);
// the only LDS is a per-wave P round-trip (C-layout -> A-frag), wave-local.
__global__ __launch_bounds__(256, 4) void k_attn(const bf16* __restrict__ Qh,
                                                 const bf16* __restrict__ Kh,
                                                 const bf16* __restrict__ Vt,
                                                 bf16* __restrict__ aout) {
  __shared__ __align__(16) unsigned short Ps[4][16 * 72];  // per-wave slice

  const int tid = threadIdx.x;
  const int w = tid >> 6, lane = tid & 63;
  const int ln = lane & 15, quad = lane >> 4;
  const int bh = blockIdx.y;
  const int qw = blockIdx.x * 64 + w * 16;  // wave's first query
  const size_t base = (size_t)bh * S_LEN * DH;
  const bf16* Qp = Qh + base;
  const bf16* Kp = Kh + base;
  const bf16* Vp = Vt + base;  // [d][s]
  unsigned short* myPs = Ps[w];

  // Q A-frags, direct from global
  const short8 aq0 = *(const short8*)(Qp + (size_t)(qw + ln) * DH + quad * 8);
  const short8 aq1 = *(const short8*)(Qp + (size_t)(qw + ln) * DH + 32 + quad * 8);

  floatx4 acc[4];  // O, C-layout: col d=dt*16+ln, row q=quad*4+r
  #pragma unroll
  for (int dt = 0; dt < 4; dt++) acc[dt] = (floatx4){0.f, 0.f, 0.f, 0.f};
  float m_i[4], l_i[4];
  #pragma unroll
  for (int r = 0; r < 4; r++) { m_i[r] = -3.0e38f; l_i[r] = 0.f; }

  const float SC2 = 0.18033688011112042f;  // 0.125 * log2(e)

  auto process = [&](int c) {
    // ---- S = Q K^T, K B-frags direct from global ----
    floatx4 s[4];
    #pragma unroll
    for (int jt = 0; jt < 4; jt++) {
      const bf16* kr = Kp + (size_t)(c + jt * 16 + ln) * DH;
      short8 bk0 = *(const short8*)(kr + quad * 8);
      short8 bk1 = *(const short8*)(kr + 32 + quad * 8);
      floatx4 z = (floatx4){0.f, 0.f, 0.f, 0.f};
      z = __builtin_amdgcn_mfma_f32_16x16x32_bf16(aq0, bk0, z, 0, 0, 0);
      s[jt] = __builtin_amdgcn_mfma_f32_16x16x32_bf16(aq1, bk1, z, 0, 0, 0);
    }
    // ---- mask + scale into exp2 domain ----
    const bool full_in = (c >= qw - 241) && (c <= qw + 193);
    if (full_in) {
      #pragma unroll
      for (int jt = 0; jt < 4; jt++)
        #pragma unroll
        for (int r = 0; r < 4; r++) s[jt][r] *= SC2;
    } else {
      #pragma unroll
      for (int jt = 0; jt < 4; jt++) {
        int j = c + jt * 16 + ln;
        #pragma unroll
        for (int r = 0; r < 4; r++) {
          int q = qw + quad * 4 + r;
          int d = q - j;
          bool ok = (d <= WIN && d >= -WIN) || (q == 0) || (j == 0);
          s[jt][r] = ok ? s[jt][r] * SC2 : -3.0e38f;
        }
      }
    }
    // ---- online softmax (row = quad*4+r, reduce over ln) ----
    float mx[4];
    #pragma unroll
    for (int r = 0; r < 4; r++)
      mx[r] = fmaxf(fmaxf(s[0][r], s[1][r]), fmaxf(s[2][r], s[3][r]));
    #pragma unroll
    for (int off = 1; off < 16; off <<= 1)
      #pragma unroll
      for (int r = 0; r < 4; r++) mx[r] = fmaxf(mx[r], __shfl_xor(mx[r], off, 64));
    float alpha[4];
    #pragma unroll
    for (int r = 0; r < 4; r++) {
      float mnew = fmaxf(m_i[r], mx[r]);
      alpha[r] = exp2f(m_i[r] - mnew);
      m_i[r] = mnew;
    }
    float ss[4] = {0.f, 0.f, 0.f, 0.f};
    #pragma unroll
    for (int jt = 0; jt < 4; jt++)
      #pragma unroll
      for (int r = 0; r < 4; r++) {
        float pe = exp2f(s[jt][r] - m_i[r]);
        unsigned short us = f2b(pe);
        myPs[(quad * 4 + r) * 72 + jt * 16 + ln] = us;
        ss[r] += __uint_as_float((unsigned)us << 16);  // sum what PV will consume
      }
    #pragma unroll
    for (int off = 1; off < 16; off <<= 1)
      #pragma unroll
      for (int r = 0; r < 4; r++) ss[r] += __shfl_xor(ss[r], off, 64);
    #pragma unroll
    for (int r = 0; r < 4; r++) l_i[r] = l_i[r] * alpha[r] + ss[r];
    #pragma unroll
    for (int dt = 0; dt < 4; dt++)
      #pragma unroll
      for (int r = 0; r < 4; r++) acc[dt][r] *= alpha[r];
    // wave-local LDS ordering: drain writes before frag reads (no cross-wave sharing)
    asm volatile("s_waitcnt lgkmcnt(0)" ::: "memory");
    short8 ap0 = *(const short8*)&myPs[ln * 72 + quad * 8];
    short8 ap1 = *(const short8*)&myPs[ln * 72 + 32 + quad * 8];
    // ---- O += P V, V^T B-frags direct from global ----
    #pragma unroll
    for (int dt = 0; dt < 4; dt++) {
      const bf16* vr = Vp + (size_t)(dt * 16 + ln) * S_LEN + c;
      short8 bv0 = *(const short8*)(vr + quad * 8);
      short8 bv1 = *(const short8*)(vr + 32 + quad * 8);
      acc[dt] = __builtin_amdgcn_mfma_f32_16x16x32_bf16(ap0, bv0, acc[dt], 0, 0, 0);
      acc[dt] = __builtin_amdgcn_mfma_f32_16x16x32_bf16(ap1, bv1, acc[dt], 0, 0, 0);
    }
  };

  // chunk 0 first (global col keeps every row's running max finite)
  process(0);
  int cs = qw - WIN; if (cs < 0) cs = 0; cs &= ~63;
  int ce = qw + 15 + WIN + 1; if (ce > S_LEN) ce = S_LEN; else ce = (ce + 63) & ~63;
  if (qw == 0) ce = S_LEN;
  for (int c = (cs < 64 ? 64 : cs); c < ce; c += 64) process(c);

  // ---- epilogue: normalize + write bf16 [b][q][h*64+d] ----
  const int b = bh >> 4, h = bh & 15;
  #pragma unroll
  for (int r = 0; r < 4; r++) {
    float inv = 1.0f / l_i[r];
    int q = qw + quad * 4 + r;
    #pragma unroll
    for (int dt = 0; dt < 4; dt++) {
      aout[(size_t)(b * S_LEN + q) * DM + h * DH + dt * 16 + ln] =
          __float2bfloat16(acc[dt][r] * inv);
    }
  }
}

// ---------- launch ----------
extern "C" void kernel_launch(void* const* d_in, const int* in_sizes, int n_in,
                              void* d_out, int out_size, void* d_ws, size_t ws_size,
                              hipStream_t stream) {
  const float* x  = (const float*)d_in[0];
  const float* Wq = (const float*)d_in[1];
  const float* bq = (const float*)d_in[2];
  const float* Wk = (const float*)d_in[3];
  const float* bk = (const float*)d_in[4];
  const float* Wv = (const float*)d_in[5];
  const float* bv = (const float*)d_in[6];
  const float* Wo = (const float*)d_in[7];
  const float* bo = (const float*)d_in[8];
  float* out = (float*)d_out;

  const size_t SEG = (size_t)4096 * 1024;
  bf16* xb = (bf16*)d_ws;
  bf16* wT = xb + SEG;
  bf16* Qh = wT + SEG;
  bf16* Kh = Qh + SEG;
  bf16* Vt = Kh + SEG;   // [bh][d][s]
  bf16* ao = Vt + SEG;

  k_convert_x<<<dim3(4096), dim3(256), 0, stream>>>((const float4*)x, (ushort4*)xb);
  k_transpose_cvt<<<dim3(32, 32, 4), dim3(32, 8), 0, stream>>>(Wq, Wk, Wv, Wo, wT);
  k_gemm<0><<<dim3(24, 32), dim3(256), 0, stream>>>(xb, wT, bq, bk, bv, Qh, Kh, Vt, nullptr);
  k_attn<<<dim3(32, 32), dim3(256), 0, stream>>>(Qh, Kh, Vt, ao);
  k_gemm<1><<<dim3(8, 32), dim3(256), 0, stream>>>(ao, wT + (size_t)3 * 1024 * 1024, bo,
                                                   nullptr, nullptr, nullptr, nullptr, nullptr, out);
}